// Round 7
// baseline (637.601 us; speedup 1.0000x reference)
//
#include <hip/hip_runtime.h>

// GCN 2-layer, R7: XCC-affine work-stealing gathers + GEMM1/GEMM2 fusion.
//   Xs = bf16(dinv ⊙ X)                        (fused into bucket_csr)
//   A1 = bf16(dinv[r]*(Xs[r] + Σ Xs[c]))       (gather1, queue Q1, in d_out)
//   Ts = bf16( relu(dinv⊙(A1@W1)+... )@W2 )    (gemm_fused: H1 via LDS)
//   out = relu(dinv[r]*(Ts[r] + Σ Ts[c]) + b2) (gather2, queue Q2)
// Gathers: slice = actual XCC_ID & 3 (s_getreg hwreg(20,0,4)); per-slice
// atomic work queues + stealing -> correctness independent of placement,
// L2 residency of the 3.2 MB feature slice in the common case.
// edge_index is int32 (JAX x64 disabled).

typedef short bf16x8 __attribute__((ext_vector_type(8)));
typedef float f32x4 __attribute__((ext_vector_type(4)));

#define LDSTRIDE 264   // 16 rows * 264 bf16 = 528 B/row: b128-aligned, 8-phase min

__device__ inline unsigned short f2bf(float f) {          // RNE
    unsigned int u = __float_as_uint(f);
    u += 0x7FFF + ((u >> 16) & 1);
    return (unsigned short)(u >> 16);
}
__device__ inline float bf2f(unsigned short h) {
    return __uint_as_float(((unsigned int)h) << 16);
}

// ---------- pass 1: bin edges by dst>>8 into fixed-capacity buckets ----------
__global__ __launch_bounds__(256) void bin_kernel(
    const int* __restrict__ src, const int* __restrict__ dst,
    int* __restrict__ bcur, unsigned long long* __restrict__ bbuf,
    int E, int cap) {
    __shared__ int cnt[256];
    __shared__ int base[256];
    int t = threadIdx.x;
    cnt[t] = 0;
    __syncthreads();
    int e0 = blockIdx.x * 4096;
    int s_[16], d_[16];
#pragma unroll
    for (int i = 0; i < 16; i++) {
        int e = e0 + i * 256 + t;
        if (e < E) {
            s_[i] = src[e]; d_[i] = dst[e];
            atomicAdd(&cnt[d_[i] >> 8], 1);
        } else d_[i] = -1;
    }
    __syncthreads();
    int c = cnt[t];
    base[t] = (c > 0) ? atomicAdd(&bcur[t], c) : 0;
    __syncthreads();
    cnt[t] = 0;
    __syncthreads();
#pragma unroll
    for (int i = 0; i < 16; i++) {
        if (d_[i] >= 0) {
            int b = d_[i] >> 8;
            int p = base[b] + atomicAdd(&cnt[b], 1);
            if (p < cap)
                bbuf[(size_t)b * cap + p] =
                    ((unsigned long long)(unsigned)d_[i] << 32) | (unsigned)s_[i];
        }
    }
}

// ---------- pass 2: per-bucket CSR + dinv + fused Xs = bf16(dinv⊙x) ----------
__global__ __launch_bounds__(256) void bucket_csr_kernel(
    const int* __restrict__ bcur, const unsigned long long* __restrict__ bbuf,
    const float* __restrict__ x,
    int* __restrict__ col, int* __restrict__ rowbeg, int* __restrict__ rowend,
    float* __restrict__ dinv, unsigned short* __restrict__ Xs, int N, int cap) {
    __shared__ int ldeg[256];
    __shared__ int lrp[256];
    __shared__ float sdv[256];
    int b = blockIdx.x, t = threadIdx.x;
    int cnt = min(bcur[b], cap);
    ldeg[t] = 0;
    __syncthreads();
    const unsigned long long* mybuf = bbuf + (size_t)b * cap;
    for (int i = t; i < cnt; i += 256)
        atomicAdd(&ldeg[(int)(mybuf[i] >> 32) & 255], 1);
    __syncthreads();
    int v = ldeg[t];
    lrp[t] = v;
    __syncthreads();
    for (int off = 1; off < 256; off <<= 1) {    // inclusive scan
        int u = (t >= off) ? lrp[t - off] : 0;
        __syncthreads();
        lrp[t] += u;
        __syncthreads();
    }
    int excl = lrp[t] - v;
    int r = b * 256 + t;
    int gbase = b * cap;
    float dv = rsqrtf((float)v + 1.0f);          // self-loop adds 1
    sdv[t] = dv;
    if (r < N) {
        rowbeg[r] = gbase + excl;
        rowend[r] = gbase + excl + v;
        dinv[r] = dv;
    }
    ldeg[t] = excl;    // reuse as cursor
    __syncthreads();
    for (int i = t; i < cnt; i += 256) {
        unsigned long long pr = mybuf[i];
        int dl = (int)(pr >> 32) & 255;
        int p = atomicAdd(&ldeg[dl], 1);
        col[gbase + p] = (int)(pr & 0xffffffffu);
    }
    // fused Xs: rows b*256..b*256+255, coalesced float4
    int rbase = b * 256;
    for (int i = t; i < 256 * 32; i += 256) {
        int rl = i >> 5;
        int gr = rbase + rl;
        if (gr >= N) break;
        float s = sdv[rl];
        float4 xv = ((const float4*)x)[(size_t)gr * 32 + (i & 31)];
        ushort4 o;
        o.x = f2bf(xv.x * s); o.y = f2bf(xv.y * s);
        o.z = f2bf(xv.z * s); o.w = f2bf(xv.w * s);
        ((ushort4*)Xs)[(size_t)gr * 32 + (i & 31)] = o;
    }
}

// ---------- both W swizzles in one launch ----------
__device__ inline void swz1(const float* W, unsigned short* Ws, int K, int N, int i) {
    int k = i / N, n = i % N;
    int KC = K >> 5;
    size_t d = ((((size_t)(n >> 4) * KC + (k >> 5)) * 64) + ((k >> 3) & 3) * 16 + (n & 15)) * 8
               + (k & 7);
    Ws[d] = f2bf(W[i]);
}
__global__ void wswz_kernel(const float* __restrict__ W1, const float* __restrict__ W2,
                            unsigned short* __restrict__ W1s, unsigned short* __restrict__ W2s) {
    int i = blockIdx.x * blockDim.x + threadIdx.x;
    if (i < 32768) swz1(W1, W1s, 128, 256, i);
    else if (i < 65536) swz1(W2, W2s, 256, 128, i - 32768);
}

// ---------- XCC-affine work-stealing sliced gather ----------
// Work item = 16 rows of one slice (32 features, 64 B). 256 thr = 16 rows x
// 16 lanes x ushort2. slice = XCC_ID & 3 -> own queue first, then steal.
__global__ __launch_bounds__(256) void gather_steal_kernel(
    const int* __restrict__ rowbeg, const int* __restrict__ rowend,
    const int* __restrict__ col, const unsigned short* __restrict__ P,
    const float* __restrict__ dinv, const float* __restrict__ bias,
    int* __restrict__ qcnt, unsigned short* __restrict__ OB,
    float* __restrict__ OF, int N) {
    __shared__ int sitem;
    int t = threadIdx.x;
    int xcc;
    asm volatile("s_getreg_b32 %0, hwreg(20, 0, 4)" : "=s"(xcc));  // HW_REG_XCC_ID
    int myslice = xcc & 3;
    const int nitems = (N + 15) >> 4;

    for (int q = 0; q < 4; q++) {
        int slice = (myslice + q) & 3;
        const unsigned short* Pf = P + slice * 32 + (t & 15) * 2;
        while (true) {
            if (t == 0) sitem = atomicAdd(&qcnt[slice], 1);
            __syncthreads();
            int item = sitem;
            __syncthreads();
            if (item >= nitems) break;
            int r = item * 16 + (t >> 4);
            if (r < N) {
                ushort2 u = *(const ushort2*)(Pf + (size_t)r * 128);
                float ax = bf2f(u.x), ay = bf2f(u.y);
                int beg = rowbeg[r], end = rowend[r];
                int i = beg;
                for (; i + 3 < end; i += 4) {
                    int c0 = col[i], c1 = col[i + 1], c2 = col[i + 2], c3 = col[i + 3];
                    ushort2 p0 = *(const ushort2*)(Pf + (size_t)c0 * 128);
                    ushort2 p1 = *(const ushort2*)(Pf + (size_t)c1 * 128);
                    ushort2 p2 = *(const ushort2*)(Pf + (size_t)c2 * 128);
                    ushort2 p3 = *(const ushort2*)(Pf + (size_t)c3 * 128);
                    ax += bf2f(p0.x) + bf2f(p1.x) + bf2f(p2.x) + bf2f(p3.x);
                    ay += bf2f(p0.y) + bf2f(p1.y) + bf2f(p2.y) + bf2f(p3.y);
                }
                for (; i < end; i++) {
                    ushort2 p = *(const ushort2*)(Pf + (size_t)col[i] * 128);
                    ax += bf2f(p.x); ay += bf2f(p.y);
                }
                float s = dinv[r];
                int fb = slice * 32 + (t & 15) * 2;
                if (OB) {
                    ushort2 o;
                    o.x = f2bf(ax * s); o.y = f2bf(ay * s);
                    *(ushort2*)(OB + (size_t)r * 128 + fb) = o;
                } else {
                    float2 bb = *(const float2*)(bias + fb);
                    float2 o;
                    o.x = fmaxf(ax * s + bb.x, 0.f);
                    o.y = fmaxf(ay * s + bb.y, 0.f);
                    *(float2*)(OF + (size_t)r * 128 + fb) = o;
                }
            }
        }
    }
}

// ---------- fused GEMM: Ts = bf16( (dinv⊙relu(A1@W1+b1)) @ W2 ) ----------
// Wave = one 16-row m-tile. H1 (16x256) round-trips through padded LDS to
// convert MFMA C-layout -> A-layout.
__global__ __launch_bounds__(256) void gemm_fused_kernel(
    const unsigned short* __restrict__ A, const unsigned short* __restrict__ W1s,
    const unsigned short* __restrict__ W2s, const float* __restrict__ bias,
    const float* __restrict__ dinv, unsigned short* __restrict__ T, int M) {
    __shared__ unsigned short lh[4][16 * LDSTRIDE];   // 4 waves x 8448 B
    int wave = threadIdx.x >> 6;
    int lane = threadIdx.x & 63;
    int mt = blockIdx.x * 4 + wave;
    int m0 = mt * 16;
    bool active = (m0 < M);
    int mrow = lane & 15, quad = lane >> 4;
    unsigned short* myl = lh[wave];

    if (active) {
        bf16x8 a[4];
        const unsigned short* arow = A + (size_t)(m0 + mrow) * 128 + quad * 8;
#pragma unroll
        for (int kc = 0; kc < 4; kc++) a[kc] = *(const bf16x8*)(arow + kc * 32);
        float dv[4];
#pragma unroll
        for (int i = 0; i < 4; i++) {
            int gr = m0 + quad * 4 + i;
            dv[i] = dinv[gr < M ? gr : M - 1];
        }
        const bf16x8* w1v = (const bf16x8*)W1s;
        for (int nt = 0; nt < 16; nt++) {
            f32x4 acc = {0.f, 0.f, 0.f, 0.f};
#pragma unroll
            for (int kc = 0; kc < 4; kc++) {
                bf16x8 b = w1v[(nt * 4 + kc) * 64 + lane];
                acc = __builtin_amdgcn_mfma_f32_16x16x32_bf16(a[kc], b, acc, 0, 0, 0);
            }
            int colc = nt * 16 + mrow;
            float bb = bias[colc];
#pragma unroll
            for (int i = 0; i < 4; i++) {
                float v = fmaxf(acc[i] + bb, 0.f) * dv[i];
                myl[(quad * 4 + i) * LDSTRIDE + colc] = f2bf(v);
            }
        }
    }
    __syncthreads();
    if (active) {
        bf16x8 h[8];
        const unsigned short* hrow = myl + mrow * LDSTRIDE + quad * 8;
#pragma unroll
        for (int kc = 0; kc < 8; kc++) h[kc] = *(const bf16x8*)(hrow + kc * 32);
        const bf16x8* w2v = (const bf16x8*)W2s;
        for (int nt = 0; nt < 8; nt++) {
            f32x4 acc = {0.f, 0.f, 0.f, 0.f};
#pragma unroll
            for (int kc = 0; kc < 8; kc++) {
                bf16x8 b = w2v[(nt * 8 + kc) * 64 + lane];
                acc = __builtin_amdgcn_mfma_f32_16x16x32_bf16(h[kc], b, acc, 0, 0, 0);
            }
            int colc = nt * 16 + mrow;
#pragma unroll
            for (int i = 0; i < 4; i++) {
                int gr = m0 + quad * 4 + i;
                if (gr < M) T[(size_t)gr * 128 + colc] = f2bf(acc[i]);
            }
        }
    }
}

extern "C" void kernel_launch(void* const* d_in, const int* in_sizes, int n_in,
                              void* d_out, int out_size, void* d_ws, size_t ws_size,
                              hipStream_t stream) {
    const float* x  = (const float*)d_in[0];
    const int* ei   = (const int*)d_in[1];     // int32 (JAX x64 disabled)
    const float* W1 = (const float*)d_in[2];
    const float* b1 = (const float*)d_in[3];
    const float* W2 = (const float*)d_in[4];
    const float* b2 = (const float*)d_in[5];
    float* out      = (float*)d_out;

    const int N = in_sizes[0] / 128;
    const int E = in_sizes[1] / 2;
    const int* src = ei;
    const int* dst = ei + E;

    const int nbuck = (N + 255) >> 8;                       // 196
    const int cap = E / nbuck + E / (4 * nbuck) + 1024;     // ~6125

    // Workspace: dinv | Ts | Xs | W1s | W2s | rowbeg | rowend | ctrl | bbuf | col
    float* ws = (float*)d_ws;
    size_t Np = ((size_t)N + 255) & ~(size_t)255;
    float*          dinv = ws;
    unsigned short* Ts   = (unsigned short*)(dinv + Np);    // N*128 bf16
    unsigned short* Xs   = Ts + (size_t)N * 128;            // N*128 bf16
    unsigned short* W1s  = Xs + (size_t)N * 128;            // 32768
    unsigned short* W2s  = W1s + 32768;                     // 32768
    int* rowbeg = (int*)(W2s + 32768);                      // N
    int* rowend = rowbeg + Np;                              // N
    int* ctrl   = rowend + Np;                              // bcur[256] q1[4] q2[4] -> 512
    int* bcur   = ctrl;
    int* q1     = ctrl + 256;
    int* q2     = ctrl + 260;
    unsigned long long* bbuf = (unsigned long long*)(ctrl + 512);  // nbuck*cap pairs
    int* col    = (int*)(bbuf + (size_t)nbuck * cap);       // nbuck*cap
    unsigned short* A1 = (unsigned short*)d_out;            // N*128 bf16 scratch

    // 1. control zero + bucketed CSR + dinv + Xs
    hipMemsetAsync(ctrl, 0, 512 * sizeof(int), stream);
    bin_kernel<<<(E + 4095) / 4096, 256, 0, stream>>>(src, dst, bcur, bbuf, E, cap);
    bucket_csr_kernel<<<nbuck, 256, 0, stream>>>(bcur, bbuf, x, col, rowbeg, rowend,
                                                 dinv, Xs, N, cap);

    // 2. weight swizzles (one launch)
    wswz_kernel<<<256, 256, 0, stream>>>(W1, W2, W1s, W2s);

    // 3. gather1 (XCC-affine steal) -> A1 bf16 in d_out
    gather_steal_kernel<<<2048, 256, 0, stream>>>(rowbeg, rowend, col, Xs,
                                                  dinv, nullptr, q1, A1, nullptr, N);

    // 4. fused GEMM1+GEMM2 -> Ts
    int mtiles = (N + 15) / 16;
    gemm_fused_kernel<<<(mtiles + 3) / 4, 256, 0, stream>>>(A1, W1s, W2s, b1, dinv, Ts, N);

    // 5. gather2 (XCC-affine steal) + fused bias/relu -> out
    gather_steal_kernel<<<2048, 256, 0, stream>>>(rowbeg, rowend, col, Ts,
                                                  dinv, b2, q2, nullptr, out, N);
}

// Round 8
// 247.847 us; speedup vs baseline: 2.5726x; 2.5726x over previous
//
#include <hip/hip_runtime.h>

// GCN 2-layer, R8 = best-of(R5,R7): plain ushort4 gathers (R5 shape) +
// bucketed CSR w/ 4B packed entries + fused GEMM1->LDS->GEMM2.
//   Xs = bf16(dinv ⊙ X)                        (fused into bucket_csr)
//   A1 = bf16(dinv[r]*(Xs[r] + Σ Xs[c]))       (gather1, in d_out)
//   Ts = bf16( (dinv⊙relu(A1@W1+b1)) @ W2 )    (gemm_fused, H1 via LDS)
//   out = relu(dinv[r]*(Ts[r] + Σ Ts[c]) + b2) (gather2, fused epilogue)
// R7 lesson: no per-item global atomic queues (cross-XCD atomic latency
// serialized everything). Static work assignment only.
// edge_index is int32 (JAX x64 disabled).

typedef short bf16x8 __attribute__((ext_vector_type(8)));
typedef float f32x4 __attribute__((ext_vector_type(4)));

#define LDSTRIDE 264   // 16 rows * 264 bf16 = 528 B/row: b128-aligned, 8-phase min

__device__ inline unsigned short f2bf(float f) {          // RNE
    unsigned int u = __float_as_uint(f);
    u += 0x7FFF + ((u >> 16) & 1);
    return (unsigned short)(u >> 16);
}
__device__ inline float bf2f(unsigned short h) {
    return __uint_as_float(((unsigned int)h) << 16);
}

// ---------- W swizzle into MFMA b-frag order (device helper) ----------
__device__ inline void swz1(const float* W, unsigned short* Ws, int K, int N, int i) {
    int k = i / N, n = i % N;
    int KC = K >> 5;
    size_t d = ((((size_t)(n >> 4) * KC + (k >> 5)) * 64) + ((k >> 3) & 3) * 16 + (n & 15)) * 8
               + (k & 7);
    Ws[d] = f2bf(W[i]);
}

// ---------- pass 1: bin edges by dst>>8 (4 B packed) + wswz tail block ----------
__global__ __launch_bounds__(256) void bin_kernel(
    const int* __restrict__ src, const int* __restrict__ dst,
    int* __restrict__ bcur, unsigned int* __restrict__ bbuf,
    const float* __restrict__ W1, const float* __restrict__ W2,
    unsigned short* __restrict__ W1s, unsigned short* __restrict__ W2s,
    int E, int cap) {
    int t = threadIdx.x;
    if (blockIdx.x == gridDim.x - 1) {       // fused weight swizzle block
        for (int i = t; i < 32768; i += 256) swz1(W1, W1s, 128, 256, i);
        for (int i = t; i < 32768; i += 256) swz1(W2, W2s, 256, 128, i);
        return;
    }
    __shared__ int cnt[256];
    __shared__ int base[256];
    cnt[t] = 0;
    __syncthreads();
    int e0 = blockIdx.x * 4096;
    unsigned int p_[16];
    int b_[16];
#pragma unroll
    for (int i = 0; i < 16; i++) {
        int e = e0 + i * 256 + t;
        if (e < E) {
            int s = src[e], d = dst[e];
            b_[i] = d >> 8;
            p_[i] = ((unsigned)(d & 255) << 24) | (unsigned)s;   // N < 2^24
            atomicAdd(&cnt[b_[i]], 1);
        } else b_[i] = -1;
    }
    __syncthreads();
    int c = cnt[t];
    base[t] = (c > 0) ? atomicAdd(&bcur[t], c) : 0;
    __syncthreads();
    cnt[t] = 0;        // reuse as local cursor
    __syncthreads();
#pragma unroll
    for (int i = 0; i < 16; i++) {
        if (b_[i] >= 0) {
            int b = b_[i];
            int p = base[b] + atomicAdd(&cnt[b], 1);
            if (p < cap) bbuf[(size_t)b * cap + p] = p_[i];
        }
    }
}

// ---------- pass 2: per-bucket CSR + dinv + fused Xs = bf16(dinv⊙x) ----------
__global__ __launch_bounds__(256) void bucket_csr_kernel(
    const int* __restrict__ bcur, const unsigned int* __restrict__ bbuf,
    const float* __restrict__ x,
    int* __restrict__ col, int* __restrict__ rowbeg, int* __restrict__ rowend,
    float* __restrict__ dinv, unsigned short* __restrict__ Xs, int N, int cap) {
    __shared__ int ldeg[256];
    __shared__ int lrp[256];
    __shared__ float sdv[256];
    int b = blockIdx.x, t = threadIdx.x;
    int cnt = min(bcur[b], cap);
    ldeg[t] = 0;
    __syncthreads();
    const unsigned int* mybuf = bbuf + (size_t)b * cap;
    for (int i = t; i < cnt; i += 256)
        atomicAdd(&ldeg[mybuf[i] >> 24], 1);
    __syncthreads();
    int v = ldeg[t];
    lrp[t] = v;
    __syncthreads();
    for (int off = 1; off < 256; off <<= 1) {    // inclusive scan
        int u = (t >= off) ? lrp[t - off] : 0;
        __syncthreads();
        lrp[t] += u;
        __syncthreads();
    }
    int excl = lrp[t] - v;
    int r = b * 256 + t;
    int gbase = b * cap;
    float dv = rsqrtf((float)v + 1.0f);          // self-loop adds 1
    sdv[t] = dv;
    if (r < N) {
        rowbeg[r] = gbase + excl;
        rowend[r] = gbase + excl + v;
        dinv[r] = dv;
    }
    ldeg[t] = excl;    // reuse as cursor
    __syncthreads();
    for (int i = t; i < cnt; i += 256) {
        unsigned int pr = mybuf[i];
        int p = atomicAdd(&ldeg[pr >> 24], 1);
        col[gbase + p] = (int)(pr & 0xffffffu);
    }
    // fused Xs: rows b*256..+255, coalesced float4
    int rbase = b * 256;
    for (int i = t; i < 256 * 32; i += 256) {
        int rl = i >> 5;
        int gr = rbase + rl;
        if (gr >= N) break;
        float s = sdv[rl];
        float4 xv = ((const float4*)x)[(size_t)gr * 32 + (i & 31)];
        ushort4 o;
        o.x = f2bf(xv.x * s); o.y = f2bf(xv.y * s);
        o.z = f2bf(xv.z * s); o.w = f2bf(xv.w * s);
        ((ushort4*)Xs)[(size_t)gr * 32 + (i & 31)] = o;
    }
}

// ---------- gather (R5 shape): half-wave per row, ushort4/lane, unroll x4 ----------
// OB!=null: OB[r] = bf16(dinv[r]*acc)   (gather1)
// else:     OF[r] = relu(dinv[r]*acc + bias)   (gather2)
__global__ __launch_bounds__(256) void gather_kernel(
    const int* __restrict__ rowbeg, const int* __restrict__ rowend,
    const int* __restrict__ col, const unsigned short* __restrict__ P,
    const float* __restrict__ dinv, const float* __restrict__ bias,
    unsigned short* __restrict__ OB, float* __restrict__ OF, int N) {
    int gid = blockIdx.x * blockDim.x + threadIdx.x;
    int r = gid >> 5;
    if (r >= N) return;
    int lane = gid & 31;
    const size_t off = (size_t)lane * 4;
    const unsigned short* Pf = P + off;

    ushort4 u = *(const ushort4*)(Pf + (size_t)r * 128);
    float ax = bf2f(u.x), ay = bf2f(u.y), az = bf2f(u.z), aw = bf2f(u.w);

    int beg = rowbeg[r], end = rowend[r];
    int i = beg;
    for (; i + 3 < end; i += 4) {
        int c0 = col[i], c1 = col[i + 1], c2 = col[i + 2], c3 = col[i + 3];
        ushort4 a = *(const ushort4*)(Pf + (size_t)c0 * 128);
        ushort4 b = *(const ushort4*)(Pf + (size_t)c1 * 128);
        ushort4 c = *(const ushort4*)(Pf + (size_t)c2 * 128);
        ushort4 d = *(const ushort4*)(Pf + (size_t)c3 * 128);
        ax += bf2f(a.x) + bf2f(b.x) + bf2f(c.x) + bf2f(d.x);
        ay += bf2f(a.y) + bf2f(b.y) + bf2f(c.y) + bf2f(d.y);
        az += bf2f(a.z) + bf2f(b.z) + bf2f(c.z) + bf2f(d.z);
        aw += bf2f(a.w) + bf2f(b.w) + bf2f(c.w) + bf2f(d.w);
    }
    for (; i < end; i++) {
        ushort4 a = *(const ushort4*)(Pf + (size_t)col[i] * 128);
        ax += bf2f(a.x); ay += bf2f(a.y); az += bf2f(a.z); aw += bf2f(a.w);
    }
    float s = dinv[r];
    if (OB) {
        ushort4 o;
        o.x = f2bf(ax * s); o.y = f2bf(ay * s);
        o.z = f2bf(az * s); o.w = f2bf(aw * s);
        *(ushort4*)(OB + (size_t)r * 128 + off) = o;
    } else {
        float4 bb = *(const float4*)(bias + off);
        float4 o;
        o.x = fmaxf(ax * s + bb.x, 0.f);
        o.y = fmaxf(ay * s + bb.y, 0.f);
        o.z = fmaxf(az * s + bb.z, 0.f);
        o.w = fmaxf(aw * s + bb.w, 0.f);
        *(float4*)(OF + (size_t)r * 128 + off) = o;
    }
}

// ---------- fused GEMM: Ts = bf16( (dinv⊙relu(A1@W1+b1)) @ W2 ) ----------
__global__ __launch_bounds__(256) void gemm_fused_kernel(
    const unsigned short* __restrict__ A, const unsigned short* __restrict__ W1s,
    const unsigned short* __restrict__ W2s, const float* __restrict__ bias,
    const float* __restrict__ dinv, unsigned short* __restrict__ T, int M) {
    __shared__ unsigned short lh[4][16 * LDSTRIDE];   // 4 waves x 8448 B
    int wave = threadIdx.x >> 6;
    int lane = threadIdx.x & 63;
    int mt = blockIdx.x * 4 + wave;
    int m0 = mt * 16;
    bool active = (m0 < M);
    int mrow = lane & 15, quad = lane >> 4;
    unsigned short* myl = lh[wave];

    if (active) {
        bf16x8 a[4];
        const unsigned short* arow = A + (size_t)(m0 + mrow) * 128 + quad * 8;
#pragma unroll
        for (int kc = 0; kc < 4; kc++) a[kc] = *(const bf16x8*)(arow + kc * 32);
        float dv[4];
#pragma unroll
        for (int i = 0; i < 4; i++) {
            int gr = m0 + quad * 4 + i;
            dv[i] = dinv[gr < M ? gr : M - 1];
        }
        const bf16x8* w1v = (const bf16x8*)W1s;
        for (int nt = 0; nt < 16; nt++) {
            f32x4 acc = {0.f, 0.f, 0.f, 0.f};
#pragma unroll
            for (int kc = 0; kc < 4; kc++) {
                bf16x8 b = w1v[(nt * 4 + kc) * 64 + lane];
                acc = __builtin_amdgcn_mfma_f32_16x16x32_bf16(a[kc], b, acc, 0, 0, 0);
            }
            int colc = nt * 16 + mrow;
            float bb = bias[colc];
#pragma unroll
            for (int i = 0; i < 4; i++) {
                float v = fmaxf(acc[i] + bb, 0.f) * dv[i];
                myl[(quad * 4 + i) * LDSTRIDE + colc] = f2bf(v);
            }
        }
    }
    __syncthreads();
    if (active) {
        bf16x8 h[8];
        const unsigned short* hrow = myl + mrow * LDSTRIDE + quad * 8;
#pragma unroll
        for (int kc = 0; kc < 8; kc++) h[kc] = *(const bf16x8*)(hrow + kc * 32);
        const bf16x8* w2v = (const bf16x8*)W2s;
        for (int nt = 0; nt < 8; nt++) {
            f32x4 acc = {0.f, 0.f, 0.f, 0.f};
#pragma unroll
            for (int kc = 0; kc < 8; kc++) {
                bf16x8 b = w2v[(nt * 8 + kc) * 64 + lane];
                acc = __builtin_amdgcn_mfma_f32_16x16x32_bf16(h[kc], b, acc, 0, 0, 0);
            }
            int colc = nt * 16 + mrow;
#pragma unroll
            for (int i = 0; i < 4; i++) {
                int gr = m0 + quad * 4 + i;
                if (gr < M) T[(size_t)gr * 128 + colc] = f2bf(acc[i]);
            }
        }
    }
}

extern "C" void kernel_launch(void* const* d_in, const int* in_sizes, int n_in,
                              void* d_out, int out_size, void* d_ws, size_t ws_size,
                              hipStream_t stream) {
    const float* x  = (const float*)d_in[0];
    const int* ei   = (const int*)d_in[1];     // int32 (JAX x64 disabled)
    const float* W1 = (const float*)d_in[2];
    const float* b1 = (const float*)d_in[3];
    const float* W2 = (const float*)d_in[4];
    const float* b2 = (const float*)d_in[5];
    float* out      = (float*)d_out;

    const int N = in_sizes[0] / 128;
    const int E = in_sizes[1] / 2;
    const int* src = ei;
    const int* dst = ei + E;

    const int nbuck = (N + 255) >> 8;                       // 196
    const int cap = E / nbuck + E / (4 * nbuck) + 1024;     // ~6125 (+30σ)

    // Workspace: dinv | Ts | Xs | W1s | W2s | rowbeg | rowend | ctrl | bbuf | col
    float* ws = (float*)d_ws;
    size_t Np = ((size_t)N + 255) & ~(size_t)255;
    float*          dinv = ws;
    unsigned short* Ts   = (unsigned short*)(dinv + Np);    // N*128 bf16
    unsigned short* Xs   = Ts + (size_t)N * 128;            // N*128 bf16
    unsigned short* W1s  = Xs + (size_t)N * 128;            // 32768
    unsigned short* W2s  = W1s + 32768;                     // 32768
    int* rowbeg = (int*)(W2s + 32768);                      // N
    int* rowend = rowbeg + Np;                              // N
    int* ctrl   = rowend + Np;                              // bcur[256]
    int* bcur   = ctrl;
    unsigned int* bbuf = (unsigned int*)(ctrl + 256);       // nbuck*cap packed
    int* col    = (int*)(bbuf + (size_t)nbuck * cap);       // nbuck*cap
    unsigned short* A1 = (unsigned short*)d_out;            // N*128 bf16 scratch

    // 1. bucketed CSR build (+wswz tail block) + dinv + Xs
    hipMemsetAsync(ctrl, 0, 256 * sizeof(int), stream);
    int nbins = (E + 4095) / 4096;
    bin_kernel<<<nbins + 1, 256, 0, stream>>>(src, dst, bcur, bbuf,
                                              W1, W2, W1s, W2s, E, cap);
    bucket_csr_kernel<<<nbuck, 256, 0, stream>>>(bcur, bbuf, x, col, rowbeg, rowend,
                                                 dinv, Xs, N, cap);

    // 2. gather1 -> A1 bf16 in d_out
    int gth = N * 32;
    gather_kernel<<<(gth + 255) / 256, 256, 0, stream>>>(rowbeg, rowend, col, Xs,
                                                         dinv, nullptr, A1, nullptr, N);

    // 3. fused GEMM1+GEMM2 -> Ts
    int mtiles = (N + 15) / 16;
    gemm_fused_kernel<<<(mtiles + 3) / 4, 256, 0, stream>>>(A1, W1s, W2s, b1, dinv, Ts, N);

    // 4. gather2 + fused bias/relu -> out
    gather_kernel<<<(gth + 255) / 256, 256, 0, stream>>>(rowbeg, rowend, col, Ts,
                                                         dinv, b2, nullptr, out, N);
}